// Round 16
// baseline (145.583 us; speedup 1.0000x reference)
//
#include <hip/hip_runtime.h>
#include <float.h>

#define N 4096
#define FI 44
#define RK 11
#define KNN 16
#define NSEL 25   // K + 9 ranks kept
#define NROW 4
#define ME 496    // padded reduction dim: 484 (c,r) + 11 bias + 1 pad
#define DBLK (N / NROW)        // 1024 dist blocks
#define PBLK (N / 8)           // 512 P1 blocks (8 nodes each, 1/wave)

typedef unsigned long long u64;
typedef unsigned int u32;

// ---------------- K0: sq norms + h transpose only (~2us) ----------------
__global__ __launch_bounds__(256) void k_prep(const float* __restrict__ h,
                                              float* __restrict__ sq,
                                              float* __restrict__ hT) {
  const int tid = threadIdx.x;
  int n = blockIdx.x * 256 + tid;
  const float4* hr = reinterpret_cast<const float4*>(h + (size_t)n * FI);
  float v[FI];
  float s = 0.f;
#pragma unroll
  for (int c4 = 0; c4 < 11; c4++) {
    float4 x = hr[c4];
    v[4*c4] = x.x; v[4*c4+1] = x.y; v[4*c4+2] = x.z; v[4*c4+3] = x.w;
    s += x.x*x.x + x.y*x.y + x.z*x.z + x.w*x.w;
  }
  sq[n] = s;
#pragma unroll
  for (int c = 0; c < FI; c++) hT[c * N + n] = v[c];   // coalesced per c
}

// ---------------- K2: dist/top-25 (blocks < 1024, R8 path verbatim)
//                    + P1 (1024..1535, 1 node/wave, <=64 VGPR)
//                    + W2T4 pack (1536..1539) ----------------
__global__ __launch_bounds__(512) void k_dist_p1(const float* __restrict__ hT,
                                                 const float* __restrict__ sq,
                                                 const float* __restrict__ mask,
                                                 int* __restrict__ ctr_idx,
                                                 int* __restrict__ nbr_idx,
                                                 const float* __restrict__ h,
                                                 const float* __restrict__ W1,
                                                 const float* __restrict__ b1,
                                                 const float* __restrict__ W2,
                                                 const float* __restrict__ b2,
                                                 float* __restrict__ P1e,
                                                 float* __restrict__ W2T4) {
  __shared__ __align__(16) float hi[NROW][FI];
  __shared__ float sqi4[NROW];
  __shared__ u32 lmin[NROW][512];     // 8 KB
  __shared__ u32 Tsh[NROW];
  __shared__ int cnts[NROW];
  __shared__ u64 cbuf[NROW][128];     // 4 KB
  const int tid = threadIdx.x;
  const int w = tid >> 6, lane = tid & 63;

  if (blockIdx.x >= DBLK + PBLK) {
    // ---------- W2T4 pack ----------
    int idx0 = (blockIdx.x - DBLK - PBLK) * 512 + tid;
    for (int idx = idx0; idx < 496 * 64; idx += 4 * 512) {
      int mc = idx >> 8;
      int fo = (idx >> 2) & 63;
      int i  = idx & 3;
      int m  = 4 * mc + i;
      float v = 0.f;
      if (fo < FI && m < 495) {
        if (m < 484) { int c = m % FI, r = m / FI; v = W2[c * 484 + r * FI + fo]; }
        else         { v = b2[(m - 484) * FI + fo]; }
      }
      W2T4[idx] = v;
    }
    return;
  }
  if (blockIdx.x >= DBLK) {
    // ---------- P1 path: wave = 1 node (hq = 44 VGPR, stays under 64) ----------
    const int n = (blockIdx.x - DBLK) * 8 + w;
    const float4* h4 = reinterpret_cast<const float4*>(h);
    float4 hq[11];
#pragma unroll
    for (int c4 = 0; c4 < 11; c4++) hq[c4] = h4[(size_t)n * 11 + c4];  // broadcast
    float* P1r = P1e + (size_t)n * ME;
#pragma unroll
    for (int i = 0; i < 8; i++) {
      int m = lane + 64 * i;
      if (m < 495) {
        const float4* wrow = reinterpret_cast<const float4*>(
            (m < 484) ? W1 + (size_t)(m % FI) * 484 + (m / FI) * FI
                      : b1 + (size_t)(m - 484) * FI);
        float a = 0.f;
#pragma unroll
        for (int c4 = 0; c4 < 11; c4++) {
          float4 wv = wrow[c4];
          a += wv.x*hq[c4].x + wv.y*hq[c4].y + wv.z*hq[c4].z + wv.w*hq[c4].w;
        }
        P1r[m] = a;
      }
    }
    return;
  }

  // ---------- dist path (R8/R15 proven: 64 VGPR, ~54us standalone) ----------
  const int r0 = blockIdx.x * NROW;

  if (tid < NROW) { cnts[tid] = 0; sqi4[tid] = sq[r0 + tid]; }
  for (int t = tid; t < NROW * FI; t += 512) {
    int rr = t / FI, c = t % FI;
    hi[rr][c] = hT[c * N + (r0 + rr)];
  }
  __syncthreads();

  // prefetch mask + sq (latency hides under sweep)
  const float4* sq4p = reinterpret_cast<const float4*>(sq);
  const float4* mask4 = reinterpret_cast<const float4*>(mask);
  float4 m4r[2][NROW];
  float4 sq4r[2];
#pragma unroll
  for (int s = 0; s < 2; s++) {
    sq4r[s] = sq4p[s * 512 + tid];
#pragma unroll
    for (int rr = 0; rr < NROW; rr++)
      m4r[s][rr] = mask4[(size_t)(r0 + rr) * 1024 + s * 512 + tid];
  }

  const float4* hT4 = reinterpret_cast<const float4*>(hT);
  float4 acc[NROW][2];
#pragma unroll
  for (int rr = 0; rr < NROW; rr++)
#pragma unroll
    for (int s = 0; s < 2; s++) acc[rr][s] = make_float4(0.f, 0.f, 0.f, 0.f);

#pragma unroll 4
  for (int c = 0; c < FI; c++) {
    float4 v0 = hT4[c * 1024 + tid];
    float4 v1 = hT4[c * 1024 + 512 + tid];
#pragma unroll
    for (int rr = 0; rr < NROW; rr++) {
      float hc = hi[rr][c];
      acc[rr][0].x += hc * v0.x; acc[rr][0].y += hc * v0.y;
      acc[rr][0].z += hc * v0.z; acc[rr][0].w += hc * v0.w;
      acc[rr][1].x += hc * v1.x; acc[rr][1].y += hc * v1.y;
      acc[rr][1].z += hc * v1.z; acc[rr][1].w += hc * v1.w;
    }
  }

  u32 key[NROW][8];
#pragma unroll
  for (int s = 0; s < 2; s++) {
    float4 sq4 = sq4r[s];
    int jb = s * 2048 + 4 * tid;
#pragma unroll
    for (int rr = 0; rr < NROW; rr++) {
      int row = r0 + rr;
      float4 m4 = m4r[s][rr];
      float sqr = sqi4[rr];
      float d0 = fabsf(sqr + sq4.x - 2.f * acc[rr][s].x) * m4.x;
      float d1 = fabsf(sqr + sq4.y - 2.f * acc[rr][s].y) * m4.y;
      float d2 = fabsf(sqr + sq4.z - 2.f * acc[rr][s].z) * m4.z;
      float d3 = fabsf(sqr + sq4.w - 2.f * acc[rr][s].w) * m4.w;
      d0 -= (jb + 0 == row) ? 2.f : 0.f;
      d1 -= (jb + 1 == row) ? 2.f : 0.f;
      d2 -= (jb + 2 == row) ? 2.f : 0.f;
      d3 -= (jb + 3 == row) ? 2.f : 0.f;
      u32 u0 = __float_as_uint(d0); u0 ^= (u32)((int)u0 >> 31) | 0x80000000u;
      u32 u1 = __float_as_uint(d1); u1 ^= (u32)((int)u1 >> 31) | 0x80000000u;
      u32 u2 = __float_as_uint(d2); u2 ^= (u32)((int)u2 >> 31) | 0x80000000u;
      u32 u3 = __float_as_uint(d3); u3 ^= (u32)((int)u3 >> 31) | 0x80000000u;
      key[rr][s * 4 + 0] = u0; key[rr][s * 4 + 1] = u1;
      key[rr][s * 4 + 2] = u2; key[rr][s * 4 + 3] = u3;
    }
  }

#pragma unroll
  for (int rr = 0; rr < NROW; rr++) {
    u32 m = key[rr][0];
#pragma unroll
    for (int i = 1; i < 8; i++) m = key[rr][i] < m ? key[rr][i] : m;
    lmin[rr][tid] = m;
  }
  __syncthreads();

  if (w < NROW) {
    u32 g = lmin[w][lane];
#pragma unroll
    for (int k = 1; k < 8; k++) {
      u32 x = lmin[w][64 * k + lane];
      g = x < g ? x : g;
    }
#pragma unroll
    for (int kk = 2; kk <= 64; kk <<= 1)
#pragma unroll
      for (int jj = kk >> 1; jj > 0; jj >>= 1) {
        u32 o = __shfl_xor(g, jj, 64);
        bool low = (lane & jj) == 0, asc = (lane & kk) == 0;
        u32 mn = o < g ? o : g, mx = o < g ? g : o;
        g = (low == asc) ? mn : mx;
      }
    if (lane == 24) Tsh[w] = g;
  }
  __syncthreads();

#pragma unroll
  for (int rr = 0; rr < NROW; rr++) {
    u32 Tr = Tsh[rr];
#pragma unroll
    for (int s = 0; s < 2; s++)
#pragma unroll
      for (int i = 0; i < 4; i++) {
        u32 kv = key[rr][s * 4 + i];
        if (kv <= Tr) {
          int p = atomicAdd(&cnts[rr], 1);
          if (p < 128) cbuf[rr][p] = ((u64)kv << 12) | (u64)(s * 2048 + 4 * tid + i);
        }
      }
  }
  __syncthreads();

  if (w < NROW) {
    const u64 UMAX = ~0ull;
    int cnt = cnts[w];
    u64 v0 = (lane < cnt) ? cbuf[w][lane] : UMAX;
    u64 v1 = (64 + lane < cnt) ? cbuf[w][64 + lane] : UMAX;
#pragma unroll
    for (int kk = 2; kk <= 128; kk <<= 1) {
#pragma unroll
      for (int jj = kk >> 1; jj > 0; jj >>= 1) {
        if (jj >= 64) {
          bool asc = (lane & kk) == 0;
          u64 mn = v0 < v1 ? v0 : v1, mx = v0 < v1 ? v1 : v0;
          v0 = asc ? mn : mx; v1 = asc ? mx : mn;
        } else {
          bool low = (lane & jj) == 0;
          bool asc0 = (lane & kk) == 0;
          bool asc1 = ((64 + lane) & kk) == 0;
          u64 o0 = __shfl_xor(v0, jj, 64);
          v0 = (low == asc0) ? (o0 < v0 ? o0 : v0) : (o0 < v0 ? v0 : o0);
          u64 o1 = __shfl_xor(v1, jj, 64);
          v1 = (low == asc1) ? (o1 < v1 ? o1 : v1) : (o1 < v1 ? v1 : o1);
        }
      }
    }
    int row = r0 + w;
    int idx = (int)(v0 & 4095ull);
    if (lane == 0) ctr_idx[row] = idx;
    if (lane >= 9 && lane < NSEL) nbr_idx[row * KNN + (lane - 9)] = idx;
  }
}

// ---------------- K4: fused lab + t' + G + out (block = 4 nodes, 64 edges) ----------------
__global__ __launch_bounds__(256) void k_edge_out(
    const float* __restrict__ h,
    const int* __restrict__ ctr_idx, const int* __restrict__ nbr_idx,
    const float* __restrict__ W_lab, const float* __restrict__ b_lab,
    const float* __restrict__ Wl, const float* __restrict__ bl,
    const float* __restrict__ P1e,
    const float* __restrict__ W2T4,
    float* __restrict__ out)
{
  __shared__ __align__(16) float WlabT[FI][FI];   // [f][c]
  __shared__ __align__(16) float lbl[64][FI];     // labels, then lab in-place
  __shared__ __align__(16) float WlT[RK][FI];     // [r][c]
  __shared__ __align__(16) float hcs[4][FI];
  __shared__ __align__(16) float GeL[4][ME];      // 7.9 KB per-node G
  __shared__ __align__(16) float pacc[4][4][64];  // [wave][node][fo]
  __shared__ float blabS[FI];
  __shared__ float blS[RK];
  __shared__ float tfs[64][12];
  __shared__ float wexpS[64];
  __shared__ int nbrL[64];
  __shared__ int ctrL[4];
  const int tid = threadIdx.x;
  const int b = blockIdx.x;
  const float4* h4 = reinterpret_cast<const float4*>(h);

  if (tid < 64) nbrL[tid] = nbr_idx[b * 64 + tid];
  if (tid < 4) ctrL[tid] = ctr_idx[b * 4 + tid];
  if (tid < RK) blS[tid] = bl[tid];
  if (tid >= 64 && tid < 64 + FI) blabS[tid - 64] = b_lab[tid - 64];
  for (int t = tid; t < FI * FI; t += 256) {
    int c = t / FI, f = t % FI;
    WlabT[f][c] = W_lab[t];
  }
  for (int t = tid; t < FI * RK; t += 256) {
    int c = t / RK, r = t % RK;
    WlT[r][c] = Wl[t];
  }
  __syncthreads();

  if (tid < 44) {
    int nn = tid / 11, c4 = tid % 11;
    *reinterpret_cast<float4*>(&hcs[nn][4 * c4]) = h4[(size_t)ctrL[nn] * 11 + c4];
  }
  __syncthreads();
  for (int t = tid; t < 64 * 11; t += 256) {
    int e = t / 11, c4 = t % 11;
    float4 hv = h4[(size_t)nbrL[e] * 11 + c4];
    float4 hc = *reinterpret_cast<const float4*>(&hcs[e >> 4][4 * c4]);
    float4 d;
    d.x = hv.x - hc.x; d.y = hv.y - hc.y; d.z = hv.z - hc.z; d.w = hv.w - hc.w;
    *reinterpret_cast<float4*>(&lbl[e][4 * c4]) = d;
  }
  __syncthreads();

  const int e = tid >> 2;      // edge 0..63
  const int g = tid & 3;

  float4 lbr[11];
#pragma unroll
  for (int c4 = 0; c4 < 11; c4++)
    lbr[c4] = *reinterpret_cast<const float4*>(&lbl[e][4 * c4]);
  if (g == 0) {
    float s = 0.f;
#pragma unroll
    for (int c4 = 0; c4 < 11; c4++)
      s += lbr[c4].x*lbr[c4].x + lbr[c4].y*lbr[c4].y + lbr[c4].z*lbr[c4].z + lbr[c4].w*lbr[c4].w;
    wexpS[e] = expf(-s * 0.1f) * (1.0f / 16.0f);
  }

  float la[11];
#pragma unroll
  for (int u = 0; u < 11; u++) {
    int f = g + 4 * u;
    float acc = blabS[f];
#pragma unroll
    for (int c4 = 0; c4 < 11; c4++) {
      float4 wv = *reinterpret_cast<const float4*>(&WlabT[f][4 * c4]);
      acc += wv.x*lbr[c4].x + wv.y*lbr[c4].y + wv.z*lbr[c4].z + wv.w*lbr[c4].w;
    }
    la[u] = acc >= 0.f ? acc : 0.2f * acc;
  }
  __syncthreads();             // all labels reads done
#pragma unroll
  for (int u = 0; u < 11; u++) lbl[e][g + 4 * u] = la[u];
  __syncthreads();             // lab ready

  {
#pragma unroll
    for (int c4 = 0; c4 < 11; c4++)
      lbr[c4] = *reinterpret_cast<const float4*>(&lbl[e][4 * c4]);   // now lab
    const float* P1r = P1e + (size_t)nbrL[e] * ME;
    float wex = wexpS[e];
#pragma unroll
    for (int rr = 0; rr < 3; rr++) {
      int r = g + 4 * rr;
      if (r < RK) {
        float tp = 0.f, tlp = 0.f;
#pragma unroll
        for (int c4 = 0; c4 < 11; c4++) {
          float4 p4 = *reinterpret_cast<const float4*>(P1r + r * FI + 4 * c4);
          float4 w4 = *reinterpret_cast<const float4*>(&WlT[r][4 * c4]);
          float4 l4 = lbr[c4];
          tp  += l4.x*p4.x + l4.y*p4.y + l4.z*p4.z + l4.w*p4.w;
          tlp += l4.x*w4.x + l4.y*w4.y + l4.z*w4.z + l4.w*w4.w;
        }
        tfs[e][r] = (tp + P1r[484 + r]) * (tlp + blS[r]) * wex;
      }
    }
  }
  __syncthreads();

  // G phase: GeL[nn][r*44+c] = sum_k lab[e,c]*t'[e,r]; +bias sums; pad
  const int nn = tid >> 6, lane = tid & 63;
  const int w = nn;            // wave index
  if (lane < FI) {
    float acc2[RK];
#pragma unroll
    for (int r = 0; r < RK; r++) acc2[r] = 0.f;
    for (int k = 0; k < KNN; k++) {
      float lv = lbl[nn * 16 + k][lane];
#pragma unroll
      for (int r = 0; r < RK; r++) acc2[r] += lv * tfs[nn * 16 + k][r];
    }
#pragma unroll
    for (int r = 0; r < RK; r++) GeL[nn][r * FI + lane] = acc2[r];
  } else if (lane < FI + RK) {
    int r = lane - FI;
    float ss = 0.f;
    for (int k = 0; k < KNN; k++) ss += tfs[nn * 16 + k][r];
    GeL[nn][484 + r] = ss;
  } else if (lane == 55) {
    GeL[nn][495] = 0.f;
  }
  __syncthreads();

  // out phase: wave w covers mc in [w*31,(w+1)*31) for all 4 nodes
  {
    const float4* W2v = reinterpret_cast<const float4*>(W2T4);
    float a0 = 0.f, a1 = 0.f, a2 = 0.f, a3 = 0.f;
    for (int mc = w * 31; mc < (w + 1) * 31; mc++) {
      float4 wv = W2v[mc * 64 + lane];   // coalesced 1KB/wave
      float4 g0 = *reinterpret_cast<const float4*>(&GeL[0][4 * mc]);
      float4 g1 = *reinterpret_cast<const float4*>(&GeL[1][4 * mc]);
      float4 g2 = *reinterpret_cast<const float4*>(&GeL[2][4 * mc]);
      float4 g3 = *reinterpret_cast<const float4*>(&GeL[3][4 * mc]);
      a0 += wv.x*g0.x + wv.y*g0.y + wv.z*g0.z + wv.w*g0.w;
      a1 += wv.x*g1.x + wv.y*g1.y + wv.z*g1.z + wv.w*g1.w;
      a2 += wv.x*g2.x + wv.y*g2.y + wv.z*g2.z + wv.w*g2.w;
      a3 += wv.x*g3.x + wv.y*g3.y + wv.z*g3.z + wv.w*g3.w;
    }
    pacc[w][0][lane] = a0;
    pacc[w][1][lane] = a1;
    pacc[w][2][lane] = a2;
    pacc[w][3][lane] = a3;
  }
  __syncthreads();

  if (tid < 4 * FI) {
    int n2 = tid / FI, fo = tid - (tid / FI) * FI;
    out[(size_t)(b * 4 + n2) * FI + fo] =
        pacc[0][n2][fo] + pacc[1][n2][fo] + pacc[2][n2][fo] + pacc[3][n2][fo];
  }
}

extern "C" void kernel_launch(void* const* d_in, const int* in_sizes, int n_in,
                              void* d_out, int out_size, void* d_ws, size_t ws_size,
                              hipStream_t stream) {
  const float* h     = (const float*)d_in[0];
  const float* mask  = (const float*)d_in[1];
  const float* W_lab = (const float*)d_in[2];
  const float* b_lab = (const float*)d_in[3];
  const float* W1    = (const float*)d_in[4];
  const float* b1    = (const float*)d_in[5];
  const float* W2    = (const float*)d_in[6];
  const float* b2    = (const float*)d_in[7];
  const float* Wl    = (const float*)d_in[8];
  const float* bl    = (const float*)d_in[9];

  float* sqw  = (float*)d_ws;                       // [4096]
  float* hT   = sqw + N;                            // [44*4096]
  int*   ctr  = (int*)(hT + (size_t)FI * N);        // [4096]
  int*   nbr  = ctr + N;                            // [65536]
  float* P1e  = (float*)(nbr + N * KNN);            // [4096*496]
  float* W2T4 = P1e + (size_t)N * ME;               // [496*64]

  k_prep<<<16, 256, 0, stream>>>(h, sqw, hT);
  k_dist_p1<<<DBLK + PBLK + 4, 512, 0, stream>>>(hT, sqw, mask, ctr, nbr,
                                                 h, W1, b1, W2, b2, P1e, W2T4);
  k_edge_out<<<N * KNN / 64, 256, 0, stream>>>(h, ctr, nbr, W_lab, b_lab, Wl, bl, P1e, W2T4, (float*)d_out);
}

// Round 17
// 96.005 us; speedup vs baseline: 1.5164x; 1.5164x over previous
//
#include <hip/hip_runtime.h>
#include <float.h>

#define N 4096
#define FI 44
#define RK 11
#define KNN 16
#define NSEL 25   // K + 9 ranks kept
#define NROW 4
#define ME 496    // padded reduction dim: 484 (c,r) + 11 bias + 1 pad

typedef unsigned long long u64;
typedef unsigned int u32;

// ---------------- K0: fused sq norms + h transpose + weight pre-packs ----------------
// blocks 0..15: prep (sq, hT); blocks 16..79: WrG (P1 weights) + W2T4 (m-major
// packed W2eT: float4 at [mc*64+fo] holds m=4mc..4mc+3 for output column fo).
__global__ __launch_bounds__(256) void k_prep(const float* __restrict__ h,
                                              float* __restrict__ sq,
                                              float* __restrict__ hT,
                                              const float* __restrict__ W1,
                                              const float* __restrict__ b1,
                                              const float* __restrict__ W2,
                                              const float* __restrict__ b2,
                                              float* __restrict__ WrG,
                                              float* __restrict__ W2T4) {
  const int tid = threadIdx.x;
  if (blockIdx.x < 16) {
    int n = blockIdx.x * 256 + tid;
    const float4* hr = reinterpret_cast<const float4*>(h + (size_t)n * FI);
    float v[FI];
    float s = 0.f;
#pragma unroll
    for (int c4 = 0; c4 < 11; c4++) {
      float4 x = hr[c4];
      v[4*c4] = x.x; v[4*c4+1] = x.y; v[4*c4+2] = x.z; v[4*c4+3] = x.w;
      s += x.x*x.x + x.y*x.y + x.z*x.z + x.w*x.w;
    }
    sq[n] = s;
#pragma unroll
    for (int c = 0; c < FI; c++) hT[c * N + n] = v[c];   // coalesced per c
  } else {
    int idx0 = (blockIdx.x - 16) * 256 + tid;
    for (int idx = idx0; idx < 496 * FI; idx += 64 * 256) {
      int m = idx / FI, f = idx - m * FI;
      float v;
      if (m < 484)      { int c = m % FI, r = m / FI; v = W1[c * 484 + r * FI + f]; }
      else if (m < 495) { int r = m - 484; v = b1[r * FI + f]; }
      else v = 0.f;
      WrG[idx] = v;
    }
    for (int idx = idx0; idx < 496 * 64; idx += 64 * 256) {
      int mc = idx >> 8;
      int fo = (idx >> 2) & 63;
      int i  = idx & 3;
      int m  = 4 * mc + i;
      float v = 0.f;
      if (fo < FI && m < 495) {
        if (m < 484) { int c = m % FI, r = m / FI; v = W2[c * 484 + r * FI + fo]; }
        else         { v = b2[(m - 484) * FI + fo]; }
      }
      W2T4[idx] = v;
    }
  }
}

// ---------------- K2: distance rows + top-25 (round-8 proven: 64 VGPR, ~54us) ----------------
__global__ __launch_bounds__(512) void k_dist_topk(const float* __restrict__ hT,
                                                   const float* __restrict__ sq,
                                                   const float* __restrict__ mask,
                                                   int* __restrict__ ctr_idx,
                                                   int* __restrict__ nbr_idx) {
  __shared__ __align__(16) float hi[NROW][FI];
  __shared__ float sqi4[NROW];
  __shared__ u32 lmin[NROW][512];     // 8 KB
  __shared__ u32 Tsh[NROW];
  __shared__ int cnts[NROW];
  __shared__ u64 cbuf[NROW][128];     // 4 KB
  const int tid = threadIdx.x;
  const int r0 = blockIdx.x * NROW;

  if (tid < NROW) { cnts[tid] = 0; sqi4[tid] = sq[r0 + tid]; }
  for (int t = tid; t < NROW * FI; t += 512) {
    int rr = t / FI, c = t % FI;
    hi[rr][c] = hT[c * N + (r0 + rr)];
  }
  __syncthreads();

  // prefetch mask + sq (latency hides under sweep)
  const float4* sq4p = reinterpret_cast<const float4*>(sq);
  const float4* mask4 = reinterpret_cast<const float4*>(mask);
  float4 m4r[2][NROW];
  float4 sq4r[2];
#pragma unroll
  for (int s = 0; s < 2; s++) {
    sq4r[s] = sq4p[s * 512 + tid];
#pragma unroll
    for (int rr = 0; rr < NROW; rr++)
      m4r[s][rr] = mask4[(size_t)(r0 + rr) * 1024 + s * 512 + tid];
  }

  const float4* hT4 = reinterpret_cast<const float4*>(hT);
  float4 acc[NROW][2];
#pragma unroll
  for (int rr = 0; rr < NROW; rr++)
#pragma unroll
    for (int s = 0; s < 2; s++) acc[rr][s] = make_float4(0.f, 0.f, 0.f, 0.f);

#pragma unroll 4
  for (int c = 0; c < FI; c++) {
    float4 v0 = hT4[c * 1024 + tid];
    float4 v1 = hT4[c * 1024 + 512 + tid];
#pragma unroll
    for (int rr = 0; rr < NROW; rr++) {
      float hc = hi[rr][c];
      acc[rr][0].x += hc * v0.x; acc[rr][0].y += hc * v0.y;
      acc[rr][0].z += hc * v0.z; acc[rr][0].w += hc * v0.w;
      acc[rr][1].x += hc * v1.x; acc[rr][1].y += hc * v1.y;
      acc[rr][1].z += hc * v1.z; acc[rr][1].w += hc * v1.w;
    }
  }

  u32 key[NROW][8];
#pragma unroll
  for (int s = 0; s < 2; s++) {
    float4 sq4 = sq4r[s];
    int jb = s * 2048 + 4 * tid;
#pragma unroll
    for (int rr = 0; rr < NROW; rr++) {
      int row = r0 + rr;
      float4 m4 = m4r[s][rr];
      float sqr = sqi4[rr];
      float d0 = fabsf(sqr + sq4.x - 2.f * acc[rr][s].x) * m4.x;
      float d1 = fabsf(sqr + sq4.y - 2.f * acc[rr][s].y) * m4.y;
      float d2 = fabsf(sqr + sq4.z - 2.f * acc[rr][s].z) * m4.z;
      float d3 = fabsf(sqr + sq4.w - 2.f * acc[rr][s].w) * m4.w;
      d0 -= (jb + 0 == row) ? 2.f : 0.f;
      d1 -= (jb + 1 == row) ? 2.f : 0.f;
      d2 -= (jb + 2 == row) ? 2.f : 0.f;
      d3 -= (jb + 3 == row) ? 2.f : 0.f;
      u32 u0 = __float_as_uint(d0); u0 ^= (u32)((int)u0 >> 31) | 0x80000000u;
      u32 u1 = __float_as_uint(d1); u1 ^= (u32)((int)u1 >> 31) | 0x80000000u;
      u32 u2 = __float_as_uint(d2); u2 ^= (u32)((int)u2 >> 31) | 0x80000000u;
      u32 u3 = __float_as_uint(d3); u3 ^= (u32)((int)u3 >> 31) | 0x80000000u;
      key[rr][s * 4 + 0] = u0; key[rr][s * 4 + 1] = u1;
      key[rr][s * 4 + 2] = u2; key[rr][s * 4 + 3] = u3;
    }
  }

#pragma unroll
  for (int rr = 0; rr < NROW; rr++) {
    u32 m = key[rr][0];
#pragma unroll
    for (int i = 1; i < 8; i++) m = key[rr][i] < m ? key[rr][i] : m;
    lmin[rr][tid] = m;
  }
  __syncthreads();

  const int w = tid >> 6, lane = tid & 63;

  if (w < NROW) {
    u32 g = lmin[w][lane];
#pragma unroll
    for (int k = 1; k < 8; k++) {
      u32 x = lmin[w][64 * k + lane];
      g = x < g ? x : g;
    }
#pragma unroll
    for (int kk = 2; kk <= 64; kk <<= 1)
#pragma unroll
      for (int jj = kk >> 1; jj > 0; jj >>= 1) {
        u32 o = __shfl_xor(g, jj, 64);
        bool low = (lane & jj) == 0, asc = (lane & kk) == 0;
        u32 mn = o < g ? o : g, mx = o < g ? g : o;
        g = (low == asc) ? mn : mx;
      }
    if (lane == 24) Tsh[w] = g;
  }
  __syncthreads();

#pragma unroll
  for (int rr = 0; rr < NROW; rr++) {
    u32 Tr = Tsh[rr];
#pragma unroll
    for (int s = 0; s < 2; s++)
#pragma unroll
      for (int i = 0; i < 4; i++) {
        u32 kv = key[rr][s * 4 + i];
        if (kv <= Tr) {
          int p = atomicAdd(&cnts[rr], 1);
          if (p < 128) cbuf[rr][p] = ((u64)kv << 12) | (u64)(s * 2048 + 4 * tid + i);
        }
      }
  }
  __syncthreads();

  if (w < NROW) {
    const u64 UMAX = ~0ull;
    int cnt = cnts[w];
    u64 v0 = (lane < cnt) ? cbuf[w][lane] : UMAX;
    u64 v1 = (64 + lane < cnt) ? cbuf[w][64 + lane] : UMAX;
#pragma unroll
    for (int kk = 2; kk <= 128; kk <<= 1) {
#pragma unroll
      for (int jj = kk >> 1; jj > 0; jj >>= 1) {
        if (jj >= 64) {
          bool asc = (lane & kk) == 0;
          u64 mn = v0 < v1 ? v0 : v1, mx = v0 < v1 ? v1 : v0;
          v0 = asc ? mn : mx; v1 = asc ? mx : mn;
        } else {
          bool low = (lane & jj) == 0;
          bool asc0 = (lane & kk) == 0;
          bool asc1 = ((64 + lane) & kk) == 0;
          u64 o0 = __shfl_xor(v0, jj, 64);
          v0 = (low == asc0) ? (o0 < v0 ? o0 : v0) : (o0 < v0 ? v0 : o0);
          u64 o1 = __shfl_xor(v1, jj, 64);
          v1 = (low == asc1) ? (o1 < v1 ? o1 : v1) : (o1 < v1 ? v1 : o1);
        }
      }
    }
    int row = r0 + w;
    int idx = (int)(v0 & 4095ull);
    if (lane == 0) ctr_idx[row] = idx;
    if (lane >= 9 && lane < NSEL) nbr_idx[row * KNN + (lane - 9)] = idx;
  }
}

// ---------------- K3: P1e[n][m] = dot44(h[n], WrG[m]) — register-tiled ----------------
__global__ __launch_bounds__(256) void k_P1(const float* __restrict__ h,
                                            const float* __restrict__ WrG,
                                            float* __restrict__ P1e) {
  const int tid = threadIdx.x;
  const int grp = tid >> 6, lane = tid & 63;
  const int nb = blockIdx.x * 16 + grp * 4;
  const float4* h4 = reinterpret_cast<const float4*>(h);
  const float4* W4 = reinterpret_cast<const float4*>(WrG);

  float4 hq[4][11];
#pragma unroll
  for (int q = 0; q < 4; q++)
#pragma unroll
    for (int c4 = 0; c4 < 11; c4++)
      hq[q][c4] = h4[(size_t)(nb + q) * 11 + c4];

#pragma unroll
  for (int i = 0; i < 8; i++) {
    int m = lane + 64 * i;
    if (m < ME) {
      float a0 = 0.f, a1 = 0.f, a2 = 0.f, a3 = 0.f;
#pragma unroll
      for (int c4 = 0; c4 < 11; c4++) {
        float4 w = W4[m * 11 + c4];
        a0 += w.x*hq[0][c4].x + w.y*hq[0][c4].y + w.z*hq[0][c4].z + w.w*hq[0][c4].w;
        a1 += w.x*hq[1][c4].x + w.y*hq[1][c4].y + w.z*hq[1][c4].z + w.w*hq[1][c4].w;
        a2 += w.x*hq[2][c4].x + w.y*hq[2][c4].y + w.z*hq[2][c4].z + w.w*hq[2][c4].w;
        a3 += w.x*hq[3][c4].x + w.y*hq[3][c4].y + w.z*hq[3][c4].z + w.w*hq[3][c4].w;
      }
      P1e[(size_t)(nb + 0) * ME + m] = a0;
      P1e[(size_t)(nb + 1) * ME + m] = a1;
      P1e[(size_t)(nb + 2) * ME + m] = a2;
      P1e[(size_t)(nb + 3) * ME + m] = a3;
    }
  }
}

// ---------------- K4: fused lab + t' + G + out (block = 4 nodes, 64 edges) ----------------
__global__ __launch_bounds__(256) void k_edge_out(
    const float* __restrict__ h,
    const int* __restrict__ ctr_idx, const int* __restrict__ nbr_idx,
    const float* __restrict__ W_lab, const float* __restrict__ b_lab,
    const float* __restrict__ Wl, const float* __restrict__ bl,
    const float* __restrict__ P1e,
    const float* __restrict__ W2T4,
    float* __restrict__ out)
{
  __shared__ __align__(16) float WlabT[FI][FI];   // [f][c]
  __shared__ __align__(16) float lbl[64][FI];     // labels, then lab in-place
  __shared__ __align__(16) float WlT[RK][FI];     // [r][c]
  __shared__ __align__(16) float hcs[4][FI];
  __shared__ __align__(16) float GeL[4][ME];      // 7.9 KB per-node G
  __shared__ __align__(16) float pacc[4][4][64];  // [wave][node][fo]
  __shared__ float blabS[FI];
  __shared__ float blS[RK];
  __shared__ float tfs[64][12];
  __shared__ float wexpS[64];
  __shared__ int nbrL[64];
  __shared__ int ctrL[4];
  const int tid = threadIdx.x;
  const int b = blockIdx.x;
  const float4* h4 = reinterpret_cast<const float4*>(h);

  if (tid < 64) nbrL[tid] = nbr_idx[b * 64 + tid];
  if (tid < 4) ctrL[tid] = ctr_idx[b * 4 + tid];
  if (tid < RK) blS[tid] = bl[tid];
  if (tid >= 64 && tid < 64 + FI) blabS[tid - 64] = b_lab[tid - 64];
  for (int t = tid; t < FI * FI; t += 256) {
    int c = t / FI, f = t % FI;
    WlabT[f][c] = W_lab[t];
  }
  for (int t = tid; t < FI * RK; t += 256) {
    int c = t / RK, r = t % RK;
    WlT[r][c] = Wl[t];
  }
  __syncthreads();

  if (tid < 44) {
    int nn = tid / 11, c4 = tid % 11;
    *reinterpret_cast<float4*>(&hcs[nn][4 * c4]) = h4[(size_t)ctrL[nn] * 11 + c4];
  }
  __syncthreads();
  for (int t = tid; t < 64 * 11; t += 256) {
    int e = t / 11, c4 = t % 11;
    float4 hv = h4[(size_t)nbrL[e] * 11 + c4];
    float4 hc = *reinterpret_cast<const float4*>(&hcs[e >> 4][4 * c4]);
    float4 d;
    d.x = hv.x - hc.x; d.y = hv.y - hc.y; d.z = hv.z - hc.z; d.w = hv.w - hc.w;
    *reinterpret_cast<float4*>(&lbl[e][4 * c4]) = d;
  }
  __syncthreads();

  const int e = tid >> 2;      // edge 0..63
  const int g = tid & 3;

  float4 lbr[11];
#pragma unroll
  for (int c4 = 0; c4 < 11; c4++)
    lbr[c4] = *reinterpret_cast<const float4*>(&lbl[e][4 * c4]);
  if (g == 0) {
    float s = 0.f;
#pragma unroll
    for (int c4 = 0; c4 < 11; c4++)
      s += lbr[c4].x*lbr[c4].x + lbr[c4].y*lbr[c4].y + lbr[c4].z*lbr[c4].z + lbr[c4].w*lbr[c4].w;
    wexpS[e] = expf(-s * 0.1f) * (1.0f / 16.0f);
  }

  float la[11];
#pragma unroll
  for (int u = 0; u < 11; u++) {
    int f = g + 4 * u;
    float acc = blabS[f];
#pragma unroll
    for (int c4 = 0; c4 < 11; c4++) {
      float4 wv = *reinterpret_cast<const float4*>(&WlabT[f][4 * c4]);
      acc += wv.x*lbr[c4].x + wv.y*lbr[c4].y + wv.z*lbr[c4].z + wv.w*lbr[c4].w;
    }
    la[u] = acc >= 0.f ? acc : 0.2f * acc;
  }
  __syncthreads();             // all labels reads done
#pragma unroll
  for (int u = 0; u < 11; u++) lbl[e][g + 4 * u] = la[u];
  __syncthreads();             // lab ready

  {
#pragma unroll
    for (int c4 = 0; c4 < 11; c4++)
      lbr[c4] = *reinterpret_cast<const float4*>(&lbl[e][4 * c4]);   // now lab
    const float* P1r = P1e + (size_t)nbrL[e] * ME;
    float wex = wexpS[e];
#pragma unroll
    for (int rr = 0; rr < 3; rr++) {
      int r = g + 4 * rr;
      if (r < RK) {
        float tp = 0.f, tlp = 0.f;
#pragma unroll
        for (int c4 = 0; c4 < 11; c4++) {
          float4 p4 = *reinterpret_cast<const float4*>(P1r + r * FI + 4 * c4);
          float4 w4 = *reinterpret_cast<const float4*>(&WlT[r][4 * c4]);
          float4 l4 = lbr[c4];
          tp  += l4.x*p4.x + l4.y*p4.y + l4.z*p4.z + l4.w*p4.w;
          tlp += l4.x*w4.x + l4.y*w4.y + l4.z*w4.z + l4.w*w4.w;
        }
        tfs[e][r] = (tp + P1r[484 + r]) * (tlp + blS[r]) * wex;
      }
    }
  }
  __syncthreads();

  // G phase: GeL[nn][r*44+c] = sum_k lab[e,c]*t'[e,r]; +bias sums; pad
  const int nn = tid >> 6, lane = tid & 63;
  const int w = nn;            // wave index
  if (lane < FI) {
    float acc2[RK];
#pragma unroll
    for (int r = 0; r < RK; r++) acc2[r] = 0.f;
    for (int k = 0; k < KNN; k++) {
      float lv = lbl[nn * 16 + k][lane];
#pragma unroll
      for (int r = 0; r < RK; r++) acc2[r] += lv * tfs[nn * 16 + k][r];
    }
#pragma unroll
    for (int r = 0; r < RK; r++) GeL[nn][r * FI + lane] = acc2[r];
  } else if (lane < FI + RK) {
    int r = lane - FI;
    float ss = 0.f;
    for (int k = 0; k < KNN; k++) ss += tfs[nn * 16 + k][r];
    GeL[nn][484 + r] = ss;
  } else if (lane == 55) {
    GeL[nn][495] = 0.f;
  }
  __syncthreads();

  // out phase: wave w covers mc in [w*31,(w+1)*31) for all 4 nodes
  {
    const float4* W2v = reinterpret_cast<const float4*>(W2T4);
    float a0 = 0.f, a1 = 0.f, a2 = 0.f, a3 = 0.f;
    for (int mc = w * 31; mc < (w + 1) * 31; mc++) {
      float4 wv = W2v[mc * 64 + lane];   // coalesced 1KB/wave
      float4 g0 = *reinterpret_cast<const float4*>(&GeL[0][4 * mc]);
      float4 g1 = *reinterpret_cast<const float4*>(&GeL[1][4 * mc]);
      float4 g2 = *reinterpret_cast<const float4*>(&GeL[2][4 * mc]);
      float4 g3 = *reinterpret_cast<const float4*>(&GeL[3][4 * mc]);
      a0 += wv.x*g0.x + wv.y*g0.y + wv.z*g0.z + wv.w*g0.w;
      a1 += wv.x*g1.x + wv.y*g1.y + wv.z*g1.z + wv.w*g1.w;
      a2 += wv.x*g2.x + wv.y*g2.y + wv.z*g2.z + wv.w*g2.w;
      a3 += wv.x*g3.x + wv.y*g3.y + wv.z*g3.z + wv.w*g3.w;
    }
    pacc[w][0][lane] = a0;
    pacc[w][1][lane] = a1;
    pacc[w][2][lane] = a2;
    pacc[w][3][lane] = a3;
  }
  __syncthreads();

  if (tid < 4 * FI) {
    int n2 = tid / FI, fo = tid - (tid / FI) * FI;
    out[(size_t)(b * 4 + n2) * FI + fo] =
        pacc[0][n2][fo] + pacc[1][n2][fo] + pacc[2][n2][fo] + pacc[3][n2][fo];
  }
}

extern "C" void kernel_launch(void* const* d_in, const int* in_sizes, int n_in,
                              void* d_out, int out_size, void* d_ws, size_t ws_size,
                              hipStream_t stream) {
  const float* h     = (const float*)d_in[0];
  const float* mask  = (const float*)d_in[1];
  const float* W_lab = (const float*)d_in[2];
  const float* b_lab = (const float*)d_in[3];
  const float* W1    = (const float*)d_in[4];
  const float* b1    = (const float*)d_in[5];
  const float* W2    = (const float*)d_in[6];
  const float* b2    = (const float*)d_in[7];
  const float* Wl    = (const float*)d_in[8];
  const float* bl    = (const float*)d_in[9];

  float* sqw  = (float*)d_ws;                       // [4096]
  float* hT   = sqw + N;                            // [44*4096]
  int*   ctr  = (int*)(hT + (size_t)FI * N);        // [4096]
  int*   nbr  = ctr + N;                            // [65536]
  float* P1e  = (float*)(nbr + N * KNN);            // [4096*496]
  float* WrG  = P1e + (size_t)N * ME;               // [496*44]
  float* W2T4 = WrG + 496 * FI;                     // [496*64]

  k_prep<<<80, 256, 0, stream>>>(h, sqw, hT, W1, b1, W2, b2, WrG, W2T4);
  k_dist_topk<<<N / NROW, 512, 0, stream>>>(hT, sqw, mask, ctr, nbr);
  k_P1<<<N / 16, 256, 0, stream>>>(h, WrG, P1e);
  k_edge_out<<<N * KNN / 64, 256, 0, stream>>>(h, ctr, nbr, W_lab, b_lab, Wl, bl, P1e, W2T4, (float*)d_out);
}